// Round 3
// baseline (464.947 us; speedup 1.0000x reference)
//
#include <hip/hip_runtime.h>
#include <math.h>

// FAVOR+ (Performer) non-causal linear attention, b=4 h=8 n=8192 d=64 f=266.
// Round 3: 1024-thread blocks (16 waves -> 4 waves/SIMD), halved per-wave work,
// in-block K-half combine for context partials, VGPR-capped at 128.

typedef __attribute__((ext_vector_type(8))) short s16x8;
typedef __attribute__((ext_vector_type(4))) float f32x4;

#define MFMA16(a,b,c) __builtin_amdgcn_mfma_f32_16x16x32_bf16((a),(b),(c),0,0,0)

__device__ __forceinline__ unsigned short bf16rne(float x){
  unsigned u = __float_as_uint(x);
  u = u + 0x7fffu + ((u >> 16) & 1u);
  return (unsigned short)(u >> 16);
}
__device__ __forceinline__ float bf16tof(unsigned short h){
  return __uint_as_float(((unsigned)h) << 16);
}
__device__ __forceinline__ void cvt_hl8(const float v[8], s16x8& h, s16x8& l){
  #pragma unroll
  for(int j=0;j<8;++j){
    unsigned short hh = bf16rne(v[j]);
    h[j] = (short)hh;
    l[j] = (short)bf16rne(v[j] - bf16tof(hh));
  }
}

// ---------------- prep: scaled/padded proj hi/lo ----------------
__global__ void fa21_prep(const float* __restrict__ proj, short* __restrict__ ph,
                          short* __restrict__ pl, float pscale){
  int idx = blockIdx.x*256 + threadIdx.x;
  if(idx >= 288*64) return;
  int f = idx >> 6, dc = idx & 63;
  float v = (f < 266) ? proj[f*64 + dc]*pscale : 0.f;
  unsigned short hh = bf16rne(v);
  ph[idx] = (short)hh;
  pl[idx] = (short)bf16rne(v - bf16tof(hh));
}

// ---------------- phase 1: kp -> context partials + ksum partials ----------------
// grid 256 = 32 heads x 8 chunks, 1024 threads (16 waves), 8 iters of 128 rows.
// phi role: wave = (mt8 = w>>1 in 0..7, fh = w&1). ctx role: (kh=w&1, et=(w>>1)&3, fhc=(w>>3)&1).
// LDS: proj h/l [288][64] swz(f&7) = 72K, kp hi f-major [288][128] swz(f&15) = 72K, sks [8][288].
__global__ __launch_bounds__(1024,4) void fa21_p1(
    const float* __restrict__ kin, const float* __restrict__ vin,
    const short* __restrict__ pjh, const short* __restrict__ pjl,
    float* __restrict__ ctx_part, float* __restrict__ ksum_part,
    float koff, float diagc){
  extern __shared__ char smem[];
  char* sph = smem;
  char* spl = smem + 36864;
  char* skh = smem + 73728;
  float* sks = (float*)(smem + 147456);
  const int tid = threadIdx.x;
  const int w = tid >> 6, lane = tid & 63, g = lane >> 4, q = lane & 15;
  const int bid = blockIdx.x;
  const int head = bid & 31, chunk = bid >> 5;
  for(int i = tid; i < 288*64; i += 1024){
    int f = i >> 6, dc = i & 63;
    int byt = (f*128 + dc*2) ^ ((f & 7) << 4);
    *(short*)(sph + byt) = pjh[i];
    *(short*)(spl + byt) = pjl[i];
  }
  __syncthreads();
  const int mt8 = w >> 1, fh = w & 1;
  const int kh = w & 1, et = (w >> 1) & 3, fhc = (w >> 3) & 1;
  f32x4 acc[9];
  #pragma unroll
  for(int a=0;a<9;++a){ f32x4 z = {0.f,0.f,0.f,0.f}; acc[a] = z; }
  float ksacc[9];
  #pragma unroll
  for(int a=0;a<9;++a) ksacc[a] = 0.f;
  const float* kbase = kin + (size_t)head*8192*64;
  const float* vbase = vin + (size_t)head*8192*64;
  #pragma unroll 1
  for(int it = 0; it < 8; ++it){
    const int nb = chunk*1024 + it*128;
    // ---- X A-frags: rows mt8*16+q, k=d contiguous per lane
    s16x8 xh[2], xl[2];
    float diag;
    {
      const float* rp = kbase + (size_t)(nb + mt8*16 + q)*64;
      float ss = 0.f;
      #pragma unroll
      for(int ks=0; ks<2; ++ks){
        float4 a = *(const float4*)(rp + ks*32 + g*8);
        float4 b = *(const float4*)(rp + ks*32 + g*8 + 4);
        float vv[8] = {a.x,a.y,a.z,a.w,b.x,b.y,b.z,b.w};
        #pragma unroll
        for(int j=0;j<8;++j) ss += vv[j]*vv[j];
        cvt_hl8(vv, xh[ks], xl[ks]);
      }
      ss += __shfl_xor(ss, 16); ss += __shfl_xor(ss, 32);
      diag = ss * diagc;
    }
    float dro[4];
    #pragma unroll
    for(int i=0;i<4;++i) dro[i] = __shfl(diag, 4*g + i) - koff;
    // ---- phi: S = X * projT (3-product), this wave's 9 f-tiles
    f32x4 S[9];
    #pragma unroll
    for(int ftl=0;ftl<9;++ftl){ f32x4 z = {0.f,0.f,0.f,0.f}; S[ftl] = z; }
    #pragma unroll
    for(int ftl=0; ftl<9; ++ftl){
      const int f = (fh*9 + ftl)*16 + q;
      #pragma unroll
      for(int ks=0; ks<2; ++ks){
        int byt = (f*128 + ks*64 + g*16) ^ ((f & 7) << 4);
        s16x8 bph = *(const s16x8*)(sph + byt);
        s16x8 bpl = *(const s16x8*)(spl + byt);
        S[ftl] = MFMA16(xh[ks], bph, S[ftl]);
        S[ftl] = MFMA16(xl[ks], bph, S[ftl]);
        S[ftl] = MFMA16(xh[ks], bpl, S[ftl]);
      }
    }
    // ---- kp = exp2(S - diag + koff), mask, ksum, pack hi -> LDS f-major swz
    #pragma unroll
    for(int ftl=0; ftl<9; ++ftl){
      const int f = (fh*9 + ftl)*16 + q;
      const bool live = (f < 266);
      float p[4];
      #pragma unroll
      for(int i=0;i<4;++i){
        float e = exp2f(S[ftl][i] - dro[i]);
        p[i] = live ? e : 0.f;
      }
      ksacc[ftl] += p[0]+p[1]+p[2]+p[3];
      uint2 hv;
      hv.x = (unsigned)bf16rne(p[0]) | ((unsigned)bf16rne(p[1]) << 16);
      hv.y = (unsigned)bf16rne(p[2]) | ((unsigned)bf16rne(p[3]) << 16);
      int byt = (f*256 + (mt8*16 + 4*g)*2) ^ ((f & 15) << 4);
      *(uint2*)(skh + byt) = hv;
    }
    // ---- V B-frags: this wave's e-tile, its K-half (2 slices of 32 rows)
    s16x8 vh[2], vl[2];
    {
      const int e = et*16 + q;
      #pragma unroll
      for(int s2=0; s2<2; ++s2){
        const int s = kh*2 + s2;
        float vv[8];
        #pragma unroll
        for(int i2=0;i2<8;++i2) vv[i2] = vbase[(size_t)(nb + s*32 + 8*g + i2)*64 + e];
        cvt_hl8(vv, vh[s2], vl[s2]);
      }
    }
    __syncthreads();   // kp ready
    // ---- context += kpT * V (2-product), this wave's (kh, et, fhc)
    #pragma unroll
    for(int fm=0; fm<9; ++fm){
      const int fg = (fhc*9 + fm)*16 + q;
      #pragma unroll
      for(int s2=0; s2<2; ++s2){
        const int s = kh*2 + s2;
        int byt = (fg*256 + s*64 + 16*g) ^ ((fg & 15) << 4);
        s16x8 kf = *(const s16x8*)(skh + byt);
        acc[fm] = MFMA16(kf, vh[s2], acc[fm]);
        acc[fm] = MFMA16(kf, vl[s2], acc[fm]);
      }
    }
    __syncthreads();   // kp LDS reusable
  }
  // ---- ksum partials: g-reduce, one writer per (mt8, f)
  #pragma unroll
  for(int ftl=0; ftl<9; ++ftl){
    float s = ksacc[ftl];
    s += __shfl_xor(s, 16); s += __shfl_xor(s, 32);
    if(g == 0) sks[mt8*288 + (fh*9 + ftl)*16 + q] = s;
  }
  // ---- K-half combine of ctx partials through (now free) kp LDS
  float* ex = (float*)skh;
  const int base = ((w >> 1) & 7) * 2304;
  if(kh == 1){
    #pragma unroll
    for(int fm=0; fm<9; ++fm){
      #pragma unroll
      for(int i=0;i<4;++i) ex[base + fm*256 + (4*g + i)*16 + q] = acc[fm][i];
    }
  }
  __syncthreads();
  if(kh == 0){
    float* cp = ctx_part + (size_t)bid*288*64;
    #pragma unroll
    for(int fm=0; fm<9; ++fm){
      #pragma unroll
      for(int i=0;i<4;++i){
        float vsum = acc[fm][i] + ex[base + fm*256 + (4*g + i)*16 + q];
        int f = (fhc*9 + fm)*16 + 4*g + i;
        cp[f*64 + et*16 + q] = vsum;
      }
    }
  }
  for(int i = tid; i < 288; i += 1024){
    float s = 0.f;
    #pragma unroll
    for(int m=0; m<8; ++m) s += sks[m*288 + i];
    ksum_part[(size_t)bid*288 + i] = s;
  }
}

// ---------------- reduce: sum 8 chunk partials -> cT hi/lo (e-major) + ksum ----------------
__global__ void fa21_reduce(const float* __restrict__ ctx_part, const float* __restrict__ ksum_part,
                            short* __restrict__ cth, short* __restrict__ ctl, float* __restrict__ ksum){
  int h = blockIdx.x, tid = threadIdx.x;
  for(int idx = tid; idx < 288*64; idx += 256){
    float s = 0.f;
    #pragma unroll
    for(int c=0;c<8;++c) s += ctx_part[(size_t)(h + 32*c)*288*64 + idx];
    int f = idx >> 6, e = idx & 63;
    unsigned short hh = bf16rne(s);
    cth[(size_t)h*64*288 + e*288 + f] = (short)hh;
    ctl[(size_t)h*64*288 + e*288 + f] = (short)bf16rne(s - bf16tof(hh));
  }
  for(int idx = tid; idx < 288; idx += 256){
    float s = 0.f;
    #pragma unroll
    for(int c=0;c<8;++c) s += ksum_part[(size_t)(h + 32*c)*288 + idx];
    ksum[h*288 + idx] = s;
  }
}

// ---------------- phase 2: qp -> out ----------------
// grid 256, 1024 threads (16 waves), 8 iters of 128 rows.
// phi role: (mt8 = w>>1, fh = w&1). out role: (mq = w>>1, eh = w&1).
// LDS: proj h/l 72K, qp hi n-major [128][296], rmx[2][128], dnb[2][128].
__global__ __launch_bounds__(1024,4) void fa21_p2(
    const float* __restrict__ qin,
    const short* __restrict__ pjh, const short* __restrict__ pjl,
    const short* __restrict__ cth, const short* __restrict__ ctl,
    const float* __restrict__ ksum, float* __restrict__ outp,
    float qoff, float qeps, float diagc){
  extern __shared__ char smem[];
  char* sph = smem;
  char* spl = smem + 36864;
  char* sqh = smem + 73728;
  float* rmx = (float*)(smem + 149504);
  float* dnb = (float*)(smem + 150528);
  const int tid = threadIdx.x;
  const int w = tid >> 6, lane = tid & 63, g = lane >> 4, q = lane & 15;
  const int bid = blockIdx.x;
  const int head = bid & 31, chunk = bid >> 5;
  for(int i = tid; i < 288*64; i += 1024){
    int f = i >> 6, dc = i & 63;
    int byt = (f*128 + dc*2) ^ ((f & 7) << 4);
    *(short*)(sph + byt) = pjh[i];
    *(short*)(spl + byt) = pjl[i];
  }
  const int mt8 = w >> 1, fh = w & 1;
  const int mq = w >> 1, eh = w & 1;
  float ksv[9];
  #pragma unroll
  for(int ftl=0; ftl<9; ++ftl) ksv[ftl] = ksum[head*288 + (fh*9 + ftl)*16 + q];
  const float* qbase = qin + (size_t)head*8192*64;
  float* obase = outp + (size_t)head*8192*64;
  const short* cbh = cth + (size_t)head*64*288;
  const short* cbl = ctl + (size_t)head*64*288;
  __syncthreads();
  #pragma unroll 1
  for(int it=0; it<8; ++it){
    const int nb = chunk*1024 + it*128;
    // ---- X A-frags: rows mt8*16+q
    s16x8 xh[2], xl[2];
    float diag;
    {
      const float* rp = qbase + (size_t)(nb + mt8*16 + q)*64;
      float ss = 0.f;
      #pragma unroll
      for(int ks=0; ks<2; ++ks){
        float4 a = *(const float4*)(rp + ks*32 + g*8);
        float4 b = *(const float4*)(rp + ks*32 + g*8 + 4);
        float vv[8] = {a.x,a.y,a.z,a.w,b.x,b.y,b.z,b.w};
        #pragma unroll
        for(int j=0;j<8;++j) ss += vv[j]*vv[j];
        cvt_hl8(vv, xh[ks], xl[ks]);
      }
      ss += __shfl_xor(ss, 16); ss += __shfl_xor(ss, 32);
      diag = ss * diagc;
    }
    // ---- phi: this wave's 9 f-tiles (3-product)
    f32x4 S[9];
    #pragma unroll
    for(int ftl=0;ftl<9;++ftl){ f32x4 z = {0.f,0.f,0.f,0.f}; S[ftl] = z; }
    #pragma unroll
    for(int ftl=0; ftl<9; ++ftl){
      const int f = (fh*9 + ftl)*16 + q;
      #pragma unroll
      for(int ks=0; ks<2; ++ks){
        int byt = (f*128 + ks*64 + g*16) ^ ((f & 7) << 4);
        s16x8 bph = *(const s16x8*)(sph + byt);
        s16x8 bpl = *(const s16x8*)(spl + byt);
        S[ftl] = MFMA16(xh[ks], bph, S[ftl]);
        S[ftl] = MFMA16(xl[ks], bph, S[ftl]);
        S[ftl] = MFMA16(xh[ks], bpl, S[ftl]);
      }
    }
    // ---- rowmax partial over this f-half -> LDS
    #pragma unroll
    for(int i=0;i<4;++i){
      float m = -3e38f;
      #pragma unroll
      for(int ftl=0; ftl<9; ++ftl){
        const int f = (fh*9 + ftl)*16 + q;
        float v = (f < 266) ? S[ftl][i] : -3e38f;
        m = fmaxf(m, v);
      }
      m = fmaxf(m, __shfl_xor(m, 1));
      m = fmaxf(m, __shfl_xor(m, 2));
      m = fmaxf(m, __shfl_xor(m, 4));
      m = fmaxf(m, __shfl_xor(m, 8));
      if(q == i) rmx[fh*128 + mt8*16 + 4*g + i] = m;
    }
    __syncthreads();  // bar1: rowmax ready
    float dro[4];
    #pragma unroll
    for(int i=0;i<4;++i){
      int row = mt8*16 + 4*g + i;
      float rm = fmaxf(rmx[row], rmx[128 + row]);
      dro[i] = __shfl(diag, 4*g + i) + rm - qoff;
    }
    // ---- qp = exp2(S - dro) + qeps, denom partial, write hi -> LDS n-major
    float dnp[4] = {0.f,0.f,0.f,0.f};
    #pragma unroll
    for(int ftl=0; ftl<9; ++ftl){
      const int f = (fh*9 + ftl)*16 + q;
      const bool live = (f < 266);
      #pragma unroll
      for(int i=0;i<4;++i){
        float e = exp2f(S[ftl][i] - dro[i]) + qeps;
        float p = live ? e : 0.f;
        dnp[i] += p * ksv[ftl];
        int n = mt8*16 + 4*g + i;
        *(short*)(sqh + n*592 + f*2) = (short)bf16rne(p);
      }
    }
    #pragma unroll
    for(int i=0;i<4;++i){
      float s = dnp[i];
      s += __shfl_xor(s, 1); s += __shfl_xor(s, 2);
      s += __shfl_xor(s, 4); s += __shfl_xor(s, 8);
      if(q == i) dnb[fh*128 + mt8*16 + 4*g + i] = s;
    }
    __syncthreads();  // bar2: qp + denom ready
    // ---- out GEMM: wave (mq, eh): 16 rows x 32 e-cols, K=288, 2-product
    f32x4 oacc[2];
    { f32x4 z = {0.f,0.f,0.f,0.f}; oacc[0] = z; oacc[1] = z; }
    #pragma unroll
    for(int ks=0; ks<9; ++ks){
      int abyt = (mq*16 + q)*592 + ks*64 + 16*g;
      s16x8 ah = *(const s16x8*)(sqh + abyt);
      #pragma unroll
      for(int e2=0; e2<2; ++e2){
        const int e = (eh*2 + e2)*16 + q;
        s16x8 ch = *(const s16x8*)(cbh + (size_t)e*288 + ks*32 + 8*g);
        s16x8 cl = *(const s16x8*)(cbl + (size_t)e*288 + ks*32 + 8*g);
        oacc[e2] = MFMA16(ah, ch, oacc[e2]);
        oacc[e2] = MFMA16(ah, cl, oacc[e2]);
      }
    }
    #pragma unroll
    for(int e2=0; e2<2; ++e2){
      #pragma unroll
      for(int i=0;i<4;++i){
        int row = mq*16 + 4*g + i;
        float dinv = 1.0f / (dnb[row] + dnb[128 + row] + 1e-8f);
        obase[(size_t)(nb + row)*64 + (eh*2 + e2)*16 + q] = oacc[e2][i] * dinv;
      }
    }
    __syncthreads();  // bar3: qp/dnb LDS reusable
  }
}

extern "C" void kernel_launch(void* const* d_in, const int* in_sizes, int n_in,
                              void* d_out, int out_size, void* d_ws, size_t ws_size,
                              hipStream_t stream){
  const float* q    = (const float*)d_in[0];
  const float* k    = (const float*)d_in[1];
  const float* v    = (const float*)d_in[2];
  const float* proj = (const float*)d_in[3];
  float* out = (float*)d_out;
  char* ws = (char*)d_ws;
  short* wproj_h = (short*)(ws);
  short* wproj_l = (short*)(ws + 36864);
  float* wctx    = (float*)(ws + 73728);
  float* wksump  = (float*)(ws + 18948096);          // 73728 + 256*73728
  short* wct_h   = (short*)(ws + 19243008);          // + 256*288*4
  short* wct_l   = (short*)(ws + 20422656);          // + 32*64*288*2
  float* wksum   = (float*)(ws + 21602304);          // + 32*64*288*2

  const double LOG2E = 1.4426950408889634;
  const double ln_ratio = -0.5*log(266.0);
  float pscale = (float)(pow(64.0, -0.25) * LOG2E);
  float diagc  = (float)(0.0625 * LOG2E);
  float koff   = (float)((1e-4 + ln_ratio) * LOG2E);
  float qoff   = (float)(ln_ratio * LOG2E);
  float qeps   = (float)(1e-4 / sqrt(266.0));

  hipFuncSetAttribute((const void*)fa21_p1, hipFuncAttributeMaxDynamicSharedMemorySize, 156672);
  hipFuncSetAttribute((const void*)fa21_p2, hipFuncAttributeMaxDynamicSharedMemorySize, 151552);

  fa21_prep<<<72, 256, 0, stream>>>(proj, wproj_h, wproj_l, pscale);
  fa21_p1<<<256, 1024, 156672, stream>>>(k, v, wproj_h, wproj_l, wctx, wksump, koff, diagc);
  fa21_reduce<<<32, 256, 0, stream>>>(wctx, wksump, wct_h, wct_l, wksum);
  fa21_p2<<<256, 1024, 151552, stream>>>(q, wproj_h, wproj_l, wct_h, wct_l, wksum, out,
                                         qoff, qeps, diagc);
}